// Round 8
// baseline (310.091 us; speedup 1.0000x reference)
//
#include <hip/hip_runtime.h>
#include <stdint.h>

// ---------------------------------------------------------------------------
// cha_third_conv: polynomial channel expansion (L=8, orders 1..3) + 1x1 conv.
// GEMM view: M=B*H*W=12544, N=256, K=32 groups * 164 feats (padded to 192).
// Round 8: geometry+pipeline on the PROVEN r7 base (runtime packed tables,
// LDS xrow feature reads, packed uint4 chunk writes — feature math untouched):
//   1) M64xN128 blocks, 512 thr = 8 waves, part==wave -> wave-uniform 8-way
//      chunk split (no divergence), stage duplication 4x -> 2x.
//   2) double-buffered ldsA + ldsX, ONE barrier per group: iteration g =
//      {issue x(g+2) | stage A(g+1) | MFMA(g) | write-late ldsX} -> barrier.
//      MFMA (matrix pipe) overlaps stage (VALU/LDS pipes).
//   3) ROW_S 200->204: A-tile row stride 408B kills the 4-way b128 read
//      aliasing of stride-400 (2-way residual = free).
// Feature values, order, rounding: bit-identical to r7 (passed, 0.0625).
// ---------------------------------------------------------------------------

typedef short bf16x8 __attribute__((ext_vector_type(8)));
typedef float f32x4  __attribute__((ext_vector_type(4)));

__device__ __forceinline__ unsigned f2bf(float f) {
  unsigned u = __float_as_uint(f);
  return ((u + 0x7FFFu + ((u >> 16) & 1u)) >> 16) & 0xFFFFu;   // RTNE
}
__device__ __forceinline__ unsigned pk2(float lo, float hi) {
  return f2bf(lo) | (f2bf(hi) << 16);
}

#define ROW_S 204   // A-tile row stride in shorts (408 B)

// ---------------------------------------------------------------------------
// featv<K>: feature K from xrow (LDS floats) + packed RUNTIME tables (r7):
//   pairs:   xrow[a] * xrow[b]
//   triples: xrow[c0] * (xrow[a] * xrow[b])   (pair product rounds first)
// ---------------------------------------------------------------------------
template <int K>
__device__ __forceinline__ float featv(const float* __restrict__ xrow,
                                       const int* __restrict__ pAB,
                                       const int* __restrict__ tABC) {
  if constexpr (K < 8) {
    return xrow[K];
  } else if constexpr (K < 44) {
    int ab = pAB[K - 8];                        // a | b<<8 (uniform -> broadcast)
    return xrow[ab & 255] * xrow[(ab >> 8) & 255];
  } else if constexpr (K < 164) {
    int abc = tABC[K - 44];                     // c0 | a<<8 | b<<16
    float p = xrow[(abc >> 8) & 255] * xrow[(abc >> 16) & 255];
    return xrow[abc & 255] * p;
  } else {
    return 0.0f;                                // pad 164..167
  }
}

// one 16B chunk = features 8*CH .. 8*CH+7 at linear chunk position CH
template <int CH>
__device__ __forceinline__ void emit_chunk(const float* __restrict__ xrow,
                                           const int* __restrict__ pAB,
                                           const int* __restrict__ tABC,
                                           short* __restrict__ arow) {
  unsigned u0 = pk2(featv<CH * 8 + 0>(xrow, pAB, tABC), featv<CH * 8 + 1>(xrow, pAB, tABC));
  unsigned u1 = pk2(featv<CH * 8 + 2>(xrow, pAB, tABC), featv<CH * 8 + 3>(xrow, pAB, tABC));
  unsigned u2 = pk2(featv<CH * 8 + 4>(xrow, pAB, tABC), featv<CH * 8 + 5>(xrow, pAB, tABC));
  unsigned u3 = pk2(featv<CH * 8 + 6>(xrow, pAB, tABC), featv<CH * 8 + 7>(xrow, pAB, tABC));
  uint4 v; v.x = u0; v.y = u1; v.z = u2; v.w = u3;
  *reinterpret_cast<uint4*>(arow + (CH << 3)) = v;   // 16B aligned
}

// wave P stages chunks {P, P+8, P+16 (P<5)}: union over P=0..7 = 0..20 exactly
template <int P>
__device__ __forceinline__ void stage_p(const float* xrow, const int* pAB,
                                        const int* tABC, short* arow) {
  emit_chunk<P>(xrow, pAB, tABC, arow);
  emit_chunk<P + 8>(xrow, pAB, tABC, arow);
  if constexpr (P < 5) emit_chunk<P + 16>(xrow, pAB, tABC, arow);
}

__device__ __forceinline__ void stage_dispatch(int wv, const float* xrow,
                                               const int* pAB, const int* tABC,
                                               short* arow) {
  switch (wv) {   // wave-uniform -> scalar branch, no divergence
    case 0: stage_p<0>(xrow, pAB, tABC, arow); break;
    case 1: stage_p<1>(xrow, pAB, tABC, arow); break;
    case 2: stage_p<2>(xrow, pAB, tABC, arow); break;
    case 3: stage_p<3>(xrow, pAB, tABC, arow); break;
    case 4: stage_p<4>(xrow, pAB, tABC, arow); break;
    case 5: stage_p<5>(xrow, pAB, tABC, arow); break;
    case 6: stage_p<6>(xrow, pAB, tABC, arow); break;
    default: stage_p<7>(xrow, pAB, tABC, arow); break;
  }
}

// ---------------------------------------------------------------------------
// Prep: verbatim r0/r6/r7 (passed). weight (256 x 5248 fp32) -> bf16, padded
// 164->192/group, B-swizzled: ws[((sg*4+q)*256+n)*8+j] = w[n][g*164+s*32+q*8+j].
// ---------------------------------------------------------------------------
__global__ void prep_w(const float* __restrict__ w, short* __restrict__ wout) {
  int e = blockIdx.x * 256 + threadIdx.x;   // < 1,572,864
  int j  = e & 7;
  int n  = (e >> 3) & 255;
  int t2 = e >> 11;
  int q  = t2 & 3;
  int sg = t2 >> 2;                         // 0..191
  int g  = sg / 6;
  int s  = sg - g * 6;
  int kk = s * 32 + q * 8 + j;              // 0..191 (reference order + pad)
  float val = (kk < 164) ? w[n * 5248 + g * 164 + kk] : 0.0f;
  wout[e] = (short)f2bf(val);
}

// ---------------------------------------------------------------------------
// Main fused kernel. Grid: (196 M-tiles of 64) x (2 N-tiles of 128).
// Block: 512 threads = 8 waves in 2(M) x 4(N); wave tile M32 x N32.
// Stage: wave w handles chunks {w, w+8, w+16?} for its lane's pixel.
// Pipeline: dbuf ldsA + dbuf ldsX, 1 __syncthreads per group.
// ---------------------------------------------------------------------------
__global__ __launch_bounds__(512, 2) void poly_gemm(
    const float* __restrict__ in, const short* __restrict__ wbf,
    const float* __restrict__ bias, const int* __restrict__ pm2,
    const int* __restrict__ pcm, float* __restrict__ out) {
  __shared__ __align__(16) short ldsA[2][64 * ROW_S];   // 52,224 B
  __shared__ float ldsX[2][64 * 9];                     // 4,608 B (stride 9)
  __shared__ int pAB[36];                               // a | b<<8
  __shared__ int tABC[120];                             // c0 | a<<8 | b<<16

  const int tid  = threadIdx.x;
  const int lane = tid & 63;        // pixel within M64 tile
  const int wave = tid >> 6;        // 0..7: stage part AND mfma wave id
  const int quad = lane >> 4;
  const int l16  = lane & 15;
  const int wm   = wave >> 2;       // 0..1: M half (32 rows)
  const int wn   = wave & 3;        // 0..3: N quarter (32 cols)
  const int m0   = blockIdx.x * 64;
  const int n0   = blockIdx.y * 128;

  // one-time init: packed+dereferenced tables + A-tile k-pad (shorts 164..203)
  if (tid < 36)  pAB[tid] = pm2[2 * tid] | (pm2[2 * tid + 1] << 8);
  if (tid < 120) {
    int pos = pcm[2 * tid + 1];
    tABC[tid] = pcm[2 * tid] | (pm2[2 * pos] << 8) | (pm2[2 * pos + 1] << 16);
  }
  for (int i = tid; i < 2 * 64 * 40; i += 512) {
    int b   = (i >= 2560) ? 1 : 0;
    int rem = i - b * 2560;
    int row = rem / 40;
    int ss  = rem - row * 40;
    ldsA[b][row * ROW_S + 164 + ss] = 0;
  }

  f32x4 acc[2][2];
#pragma unroll
  for (int mf = 0; mf < 2; mf++)
#pragma unroll
    for (int nf = 0; nf < 2; nf++) acc[mf][nf] = (f32x4){0.f, 0.f, 0.f, 0.f};

  const unsigned bb  = (unsigned)m0 / 3136u;      // 3136 = 49*64: block in one image
  const unsigned pp0 = (unsigned)m0 - bb * 3136u;
  // thread's x-load: channel = wave, pixel = lane
  const float* xg = in + (size_t)bb * 802816u + pp0 + lane;

  // prologue: x(0) -> ldsX[0]; stage A(0); x(1) -> ldsX[1]
  ldsX[0][lane * 9 + wave] = xg[(size_t)wave * 3136u];
  __syncthreads();
  stage_dispatch(wave, &ldsX[0][lane * 9], pAB, tABC, &ldsA[0][lane * ROW_S]);
  ldsX[1][lane * 9 + wave] = xg[(size_t)(8 + wave) * 3136u];
  __syncthreads();

  for (int g = 0; g < 32; ++g) {
    // issue x(g+2) early: HBM latency hides under stage+MFMA
    float xn = 0.f;
    if (g + 2 < 32) xn = xg[(size_t)((g + 2) * 8 + wave) * 3136u];

    // stage A(g+1) from ldsX[(g+1)&1] into ldsA[(g+1)&1]
    if (g + 1 < 32)
      stage_dispatch(wave, &ldsX[(g + 1) & 1][lane * 9], pAB, tABC,
                     &ldsA[(g + 1) & 1][lane * ROW_S]);

    // MFMA(g) from ldsA[g&1] — matrix pipe overlaps stage's VALU/LDS
    const short* abuf = ldsA[g & 1];
#pragma unroll
    for (int ks = 0; ks < 6; ++ks) {
      bf16x8 af[2];
#pragma unroll
      for (int mf = 0; mf < 2; mf++) {
        int row = wm * 32 + mf * 16 + l16;
        af[mf] = *(const bf16x8*)(abuf + row * ROW_S + ks * 32 + quad * 8);
      }
      bf16x8 bfr[2];
      const int sg = g * 6 + ks;
#pragma unroll
      for (int nf = 0; nf < 2; nf++) {
        int n = n0 + wn * 32 + nf * 16 + l16;
        bfr[nf] = *(const bf16x8*)(wbf + (((size_t)(sg * 4 + quad) * 256 + n) << 3));
      }
#pragma unroll
      for (int mf = 0; mf < 2; mf++)
#pragma unroll
        for (int nf = 0; nf < 2; nf++)
          acc[mf][nf] = __builtin_amdgcn_mfma_f32_16x16x32_bf16(af[mf], bfr[nf], acc[mf][nf], 0, 0, 0);
    }

    // write-late: x(g+2) into ldsX[g&1] (its x(g) was consumed last iteration)
    if (g + 2 < 32) ldsX[g & 1][lane * 9 + wave] = xn;
    __syncthreads();
  }

  // epilogue: D col = l16 (out channel), row = quad*4 + r (pixel)
#pragma unroll
  for (int nf = 0; nf < 2; nf++) {
    const int col = n0 + wn * 32 + nf * 16 + l16;
    const float bv = bias[col];
#pragma unroll
    for (int mf = 0; mf < 2; mf++) {
#pragma unroll
      for (int r = 0; r < 4; r++) {
        unsigned p2 = pp0 + (unsigned)(wm * 32 + mf * 16 + quad * 4 + r);
        out[(size_t)bb * 802816u + (size_t)col * 3136u + p2] = acc[mf][nf][r] + bv;
      }
    }
  }
}

extern "C" void kernel_launch(void* const* d_in, const int* in_sizes, int n_in,
                              void* d_out, int out_size, void* d_ws, size_t ws_size,
                              hipStream_t stream) {
  (void)in_sizes; (void)n_in; (void)out_size; (void)ws_size;
  const float* inp  = (const float*)d_in[0];
  const float* w    = (const float*)d_in[1];
  const float* bias = (const float*)d_in[2];
  const int*   pm2  = (const int*)d_in[3];
  const int*   pcm  = (const int*)d_in[4];
  short* wbf = (short*)d_ws;            // 3,145,728 B used

  prep_w<<<6144, 256, 0, stream>>>(w, wbf);
  poly_gemm<<<dim3(196, 2), 512, 0, stream>>>(inp, wbf, bias, pm2, pcm, (float*)d_out);
}

// Round 9
// 227.187 us; speedup vs baseline: 1.3649x; 1.3649x over previous
//
#include <hip/hip_runtime.h>
#include <stdint.h>

// ---------------------------------------------------------------------------
// cha_third_conv: polynomial channel expansion (L=8, orders 1..3) + 1x1 conv.
// GEMM view: M=B*H*W=12544, N=256, K=32 groups * 164 feats (padded to 192).
// Round 9: kill the stage LDS-read wall (r7 = 190us is LDS-throughput-bound:
// ~210 ds_read_b32/thread/group = 187us of LDS pipe). Features now computed
// from REGISTER x[8] in a SELF-CONSISTENT canonical order (all multisets of
// size<=3, lex): pr[36]=x[a]*x[b], triples=x[a]*pr(b,c) (pair rounds first =
// reference factorization for sorted multisets). prep_w permutes weights to
// canonical slots via monomial SIGNATURE matching against the RUNTIME
// pm2/pcm (order-independent; no reference-order derivation anywhere).
// Geometry, 2-barrier sync, MFMA core, chunk layout, epilogue: verbatim r7.
// ---------------------------------------------------------------------------

typedef short bf16x8 __attribute__((ext_vector_type(8)));
typedef float f32x4  __attribute__((ext_vector_type(4)));

__device__ __forceinline__ unsigned f2bf(float f) {
  unsigned u = __float_as_uint(f);
  return ((u + 0x7FFFu + ((u >> 16) & 1u)) >> 16) & 0xFFFFu;   // RTNE
}
__device__ __forceinline__ unsigned pk2(float lo, float hi) {
  return f2bf(lo) | (f2bf(hi) << 16);
}

#define ROW_S 200   // A-tile row stride in shorts (400 B) — r7 layout

// ---------------------------------------------------------------------------
// CANONICAL enumeration (mine, not the reference's): pairs (a<=b) lex,
// triples (a<=b<=c) lex. One constexpr table drives BOTH featc<K> and
// prep_w's signature computation -> mechanical consistency.
// ---------------------------------------------------------------------------
constexpr int PI(int b, int c) { return 8 * b - b * (b - 1) / 2 + (c - b); }

struct CTab {
  unsigned char pa[36], pb[36];          // pair slot q -> (a,b), a<=b
  unsigned char ta[120], tb[120], tc3[120]; // triple slot r -> (a,b,c) sorted
};
constexpr CTab gen_ctab() {
  CTab t{};
  int n = 0;
  for (int a = 0; a < 8; ++a)
    for (int b = a; b < 8; ++b) { t.pa[n] = (unsigned char)a; t.pb[n] = (unsigned char)b; ++n; }
  int m = 0;
  for (int a = 0; a < 8; ++a)
    for (int b = a; b < 8; ++b)
      for (int c = b; c < 8; ++c) {
        t.ta[m] = (unsigned char)a; t.tb[m] = (unsigned char)b; t.tc3[m] = (unsigned char)c; ++m;
      }
  return t;
}
constexpr CTab CT = gen_ctab();
__device__ const CTab dCT = CT;   // memory copy for prep_w

// feature K (canonical slot) from register x[8] and pair products pr[36]
template <int K>
__device__ __forceinline__ float featc(const float* __restrict__ x,
                                       const float* __restrict__ pr) {
  if constexpr (K < 8) {
    return x[K];
  } else if constexpr (K < 44) {
    return pr[K - 8];
  } else if constexpr (K < 164) {
    constexpr int r = K - 44;
    constexpr int a = CT.ta[r], b = CT.tb[r], c = CT.tc3[r];
    return x[a] * pr[PI(b, c)];            // pair product rounds first (as ref)
  } else {
    return 0.0f;                           // pad slots 164..167
  }
}

// one 16B chunk = canonical slots 8*CH .. 8*CH+7 at linear chunk position CH
template <int CH>
__device__ __forceinline__ void emit_chunk(const float* __restrict__ x,
                                           const float* __restrict__ pr,
                                           short* __restrict__ arow) {
  unsigned u0 = pk2(featc<CH * 8 + 0>(x, pr), featc<CH * 8 + 1>(x, pr));
  unsigned u1 = pk2(featc<CH * 8 + 2>(x, pr), featc<CH * 8 + 3>(x, pr));
  unsigned u2 = pk2(featc<CH * 8 + 4>(x, pr), featc<CH * 8 + 5>(x, pr));
  unsigned u3 = pk2(featc<CH * 8 + 6>(x, pr), featc<CH * 8 + 7>(x, pr));
  uint4 v; v.x = u0; v.y = u1; v.z = u2; v.w = u3;
  *reinterpret_cast<uint4*>(arow + (CH << 3)) = v;   // 16B aligned
}

// part0: chunks 0..10 (slots 0..87), part1: chunks 11..20 (88..167) — as r7
__device__ __forceinline__ void stage_part0(const float* x, const float* pr, short* arow) {
  emit_chunk<0>(x, pr, arow);  emit_chunk<1>(x, pr, arow);  emit_chunk<2>(x, pr, arow);
  emit_chunk<3>(x, pr, arow);  emit_chunk<4>(x, pr, arow);  emit_chunk<5>(x, pr, arow);
  emit_chunk<6>(x, pr, arow);  emit_chunk<7>(x, pr, arow);  emit_chunk<8>(x, pr, arow);
  emit_chunk<9>(x, pr, arow);  emit_chunk<10>(x, pr, arow);
}
__device__ __forceinline__ void stage_part1(const float* x, const float* pr, short* arow) {
  emit_chunk<11>(x, pr, arow); emit_chunk<12>(x, pr, arow); emit_chunk<13>(x, pr, arow);
  emit_chunk<14>(x, pr, arow); emit_chunk<15>(x, pr, arow); emit_chunk<16>(x, pr, arow);
  emit_chunk<17>(x, pr, arow); emit_chunk<18>(x, pr, arow); emit_chunk<19>(x, pr, arow);
  emit_chunk<20>(x, pr, arow);
}

// ---------------------------------------------------------------------------
// prep_w: weight (256 x 5248 fp32) -> bf16, padded 164->192/group, B-swizzled,
// PERMUTED reference->canonical via monomial signatures (sig = sum e_i<<2i):
//   ws[((sg*4+q)*256+n)*8+j] = w[n][g*164 + kmap[s*32+q*8+j]], sg=g*6+s,
//   kmap[kc] = reference index whose monomial == canonical slot kc's monomial.
// Runtime pm2/pcm define the reference side; dCT defines the canonical side.
// ---------------------------------------------------------------------------
__global__ void prep_w(const float* __restrict__ w, const int* __restrict__ pm2,
                       const int* __restrict__ pcm, short* __restrict__ wout) {
  __shared__ unsigned short rsig[164];
  __shared__ short kmap[192];
  const int tid = threadIdx.x;

  if (tid < 164) {       // reference-order signatures from RUNTIME tables
    unsigned s;
    if (tid < 8) {
      s = 1u << (2 * tid);
    } else if (tid < 44) {
      int q = tid - 8;
      s = (1u << (2 * pm2[2 * q])) + (1u << (2 * pm2[2 * q + 1]));
    } else {
      int r = tid - 44;
      int c0 = pcm[2 * r], pos = pcm[2 * r + 1];
      s = (1u << (2 * c0)) + (1u << (2 * pm2[2 * pos])) + (1u << (2 * pm2[2 * pos + 1]));
    }
    rsig[tid] = (unsigned short)s;
  }
  __syncthreads();

  if (tid < 192) {       // canonical slot -> reference position
    int kk = -1;
    if (tid < 164) {
      unsigned cs;
      if (tid < 8) {
        cs = 1u << (2 * tid);
      } else if (tid < 44) {
        int q = tid - 8;
        cs = (1u << (2 * dCT.pa[q])) + (1u << (2 * dCT.pb[q]));
      } else {
        int r = tid - 44;
        cs = (1u << (2 * dCT.ta[r])) + (1u << (2 * dCT.tb[r])) + (1u << (2 * dCT.tc3[r]));
      }
      for (int t = 0; t < 164; ++t)
        if (rsig[t] == (unsigned short)cs) { kk = t; break; }
    }
    kmap[tid] = (short)kk;
  }
  __syncthreads();

  int e = blockIdx.x * 256 + tid;           // < 1,572,864
  int j  = e & 7;
  int n  = (e >> 3) & 255;
  int t2 = e >> 11;
  int q  = t2 & 3;
  int sg = t2 >> 2;                         // 0..191
  int g  = sg / 6;
  int s  = sg - g * 6;
  int kc = s * 32 + q * 8 + j;              // canonical slot 0..191
  int kk = kmap[kc];
  float val = (kk >= 0) ? w[n * 5248 + g * 164 + kk] : 0.0f;
  wout[e] = (short)f2bf(val);
}

// ---------------------------------------------------------------------------
// Main fused kernel — r7 skeleton verbatim. Grid: (98 M-tiles of 128) x
// (4 N-tiles of 64). Block: 256 threads = 4 waves in 2(M) x 2(N).
// Stage: 2 threads/pixel, register x + canonical features, packed writes.
// Sync: 2 __syncthreads per group (proven).
// ---------------------------------------------------------------------------
__global__ __launch_bounds__(256, 2) void poly_gemm(
    const float* __restrict__ in, const short* __restrict__ wbf,
    const float* __restrict__ bias, float* __restrict__ out) {
  __shared__ __align__(16) short ldsA[128 * ROW_S];   // 51,200 B

  const int tid  = threadIdx.x;
  const int m0   = blockIdx.x * 128;
  const int n0   = blockIdx.y * 64;
  const int lane = tid & 63;
  const int wave = tid >> 6;
  const int wm   = wave >> 1;       // M half
  const int wn   = wave & 1;        // N half
  const int quad = lane >> 4;
  const int l16  = lane & 15;

  // one-time init: zero A-tile shorts 164..199 of every row (r7 verbatim)
  for (int i = tid; i < 128 * 36; i += 256) {
    int rr = i / 36, ss = 164 + (i - rr * 36);
    ldsA[rr * ROW_S + ss] = 0;
  }

  f32x4 acc[4][2];
#pragma unroll
  for (int mf = 0; mf < 4; mf++)
#pragma unroll
    for (int nf = 0; nf < 2; nf++) acc[mf][nf] = (f32x4){0.f, 0.f, 0.f, 0.f};

  const int pix  = tid & 127;
  const int part = tid >> 7;
  const int mg   = m0 + pix;
  const unsigned bb = (unsigned)mg / 3136u;
  const unsigned pp = (unsigned)mg - bb * 3136u;
  const float* xbase = in + (size_t)bb * 802816u + pp;

  // prologue: group-0 x into registers (coalesced: lane i -> pixel i)
  float xr[8];
#pragma unroll
  for (int c = 0; c < 8; ++c) xr[c] = xbase[(size_t)c * 3136u];

  for (int g = 0; g < 32; ++g) {
    // issue next group's x loads early — latency hides under stage + MFMA
    float xn[8];
    if (g < 31) {
      const float* xp = xbase + (size_t)((g + 1) * 8) * 3136u;
#pragma unroll
      for (int c = 0; c < 8; ++c) xn[c] = xp[(size_t)c * 3136u];
    }

    // stage: canonical features from register x, packed b128 chunk writes
    {
      short* arow = &ldsA[pix * ROW_S];
      float pr[36];
#pragma unroll
      for (int a = 0; a < 8; ++a)
#pragma unroll
        for (int b = a; b < 8; ++b) pr[PI(a, b)] = xr[a] * xr[b];
      if (part == 0) stage_part0(xr, pr, arow);
      else           stage_part1(xr, pr, arow);
    }
    __syncthreads();   // (b) A-tile ready

    // MFMA phase — r7 verbatim
#pragma unroll
    for (int ks = 0; ks < 6; ++ks) {
      bf16x8 af[4];
#pragma unroll
      for (int mf = 0; mf < 4; mf++) {
        int row = wm * 64 + mf * 16 + l16;
        af[mf] = *(const bf16x8*)(ldsA + row * ROW_S + ks * 32 + quad * 8);
      }
      bf16x8 bfr[2];
      const int sg = g * 6 + ks;
#pragma unroll
      for (int nf = 0; nf < 2; nf++) {
        int n = n0 + wn * 32 + nf * 16 + l16;
        bfr[nf] = *(const bf16x8*)(wbf + (((size_t)(sg * 4 + quad) * 256 + n) << 3));
      }
#pragma unroll
      for (int mf = 0; mf < 4; mf++)
#pragma unroll
        for (int nf = 0; nf < 2; nf++)
          acc[mf][nf] = __builtin_amdgcn_mfma_f32_16x16x32_bf16(af[mf], bfr[nf], acc[mf][nf], 0, 0, 0);
    }
    __syncthreads();   // (a) MFMA reads done before next stage overwrites

    if (g < 31) {
#pragma unroll
      for (int c = 0; c < 8; ++c) xr[c] = xn[c];
    }
  }

  // epilogue — r7 verbatim: D col = lane&15 (out ch), row = quad*4 + r
#pragma unroll
  for (int nf = 0; nf < 2; nf++) {
    const int col = n0 + wn * 32 + nf * 16 + l16;
    const float bv = bias[col];
#pragma unroll
    for (int mf = 0; mf < 4; mf++) {
#pragma unroll
      for (int r = 0; r < 4; r++) {
        int mg2 = m0 + wm * 64 + mf * 16 + quad * 4 + r;
        unsigned b2 = (unsigned)mg2 / 3136u;
        unsigned p2 = (unsigned)mg2 - b2 * 3136u;
        out[(size_t)b2 * 802816u + (size_t)col * 3136u + p2] = acc[mf][nf][r] + bv;
      }
    }
  }
}

extern "C" void kernel_launch(void* const* d_in, const int* in_sizes, int n_in,
                              void* d_out, int out_size, void* d_ws, size_t ws_size,
                              hipStream_t stream) {
  (void)in_sizes; (void)n_in; (void)out_size; (void)ws_size;
  const float* inp  = (const float*)d_in[0];
  const float* w    = (const float*)d_in[1];
  const float* bias = (const float*)d_in[2];
  const int*   pm2  = (const int*)d_in[3];
  const int*   pcm  = (const int*)d_in[4];
  short* wbf = (short*)d_ws;            // 3,145,728 B used

  prep_w<<<6144, 256, 0, stream>>>(w, pm2, pcm, wbf);
  poly_gemm<<<dim3(98, 4), 256, 0, stream>>>(inp, wbf, bias, (float*)d_out);
}